// Round 1
// baseline (370.596 us; speedup 1.0000x reference)
//
#include <hip/hip_runtime.h>
#include <hip/hip_bf16.h>

typedef __bf16 bf16x8 __attribute__((ext_vector_type(8)));
typedef float  f32x16 __attribute__((ext_vector_type(16)));

#define UF_D 256
#define MAP_M 64
#define B_DIM 32
#define U_DIM 512
#define S_DIM 4096

// ---------------------------------------------------------------------------
// Kernel A: ss = sum(v_w^2); scale = g / sqrt(ss) / 8 (fold the 1/sqrt(64)
// logit normalization into w, legal because relu(x)/8 == relu(x/8)).
// Emit w_bf16[64][256] and b_s[64] = b/8.
// ---------------------------------------------------------------------------
__global__ __launch_bounds__(256) void prep_kernel(
    const float* __restrict__ v_w, const float* __restrict__ g,
    const float* __restrict__ b, __bf16* __restrict__ w_bf16,
    float* __restrict__ b_s)
{
    __shared__ float red[256];
    const int t = threadIdx.x;
    const float4* v4 = (const float4*)v_w;   // 16384 f32 = 4096 float4
    float ss = 0.f;
    for (int i = t; i < 4096; i += 256) {
        float4 v = v4[i];
        ss += v.x * v.x + v.y * v.y + v.z * v.z + v.w * v.w;
    }
    red[t] = ss;
    __syncthreads();
    for (int s = 128; s > 0; s >>= 1) {
        if (t < s) red[t] += red[t + s];
        __syncthreads();
    }
    const float scale = g[0] / (sqrtf(red[0]) * 8.0f);
    for (int i = t; i < 4096; i += 256) {
        float4 v = v4[i];
        w_bf16[4 * i + 0] = (__bf16)(v.x * scale);
        w_bf16[4 * i + 1] = (__bf16)(v.y * scale);
        w_bf16[4 * i + 2] = (__bf16)(v.z * scale);
        w_bf16[4 * i + 3] = (__bf16)(v.w * scale);
    }
    if (t < MAP_M) b_s[t] = b[t] * 0.125f;
}

// ---------------------------------------------------------------------------
// Kernel B: proj[16384][64] = relu(ufeat[16384][256] @ w[64][256]^T + b_s),
// stored as bf16. 32x32x16 bf16 MFMA. 4 waves/block, 32 rows/wave, full N=64
// (2 col fragments). A fragment: lane l -> row l&31, k = (l>>5)*8 + j.
// B fragment: lane l -> col l&31, k = (l>>5)*8 + j (w is [N][K] row-major).
// ---------------------------------------------------------------------------
__global__ __launch_bounds__(256) void proj_kernel(
    const float* __restrict__ ufeat,    // [16384, 256] f32
    const __bf16* __restrict__ w,       // [64, 256] bf16 (pre-scaled)
    const float* __restrict__ b_s,      // [64] f32 (b/8)
    __bf16* __restrict__ proj)          // [16384, 64] bf16
{
    const int wave = threadIdx.x >> 6;
    const int lane = threadIdx.x & 63;
    const int r = lane & 31;
    const int kh = lane >> 5;           // 0/1 -> k offset 0/8
    const int row0 = blockIdx.x * 128 + wave * 32;

    f32x16 acc0 = {};
    f32x16 acc1 = {};

    const float* arow = ufeat + (size_t)(row0 + r) * UF_D + kh * 8;
    const __bf16* b0p = w + r * UF_D + kh * 8;          // cols 0..31
    const __bf16* b1p = w + (32 + r) * UF_D + kh * 8;   // cols 32..63

#pragma unroll
    for (int k = 0; k < UF_D; k += 16) {
        float4 a01 = *(const float4*)(arow + k);
        float4 a23 = *(const float4*)(arow + k + 4);
        bf16x8 af;
        af[0] = (__bf16)a01.x; af[1] = (__bf16)a01.y;
        af[2] = (__bf16)a01.z; af[3] = (__bf16)a01.w;
        af[4] = (__bf16)a23.x; af[5] = (__bf16)a23.y;
        af[6] = (__bf16)a23.z; af[7] = (__bf16)a23.w;
        bf16x8 bf0 = *(const bf16x8*)(b0p + k);
        bf16x8 bf1 = *(const bf16x8*)(b1p + k);
        acc0 = __builtin_amdgcn_mfma_f32_32x32x16_bf16(af, bf0, acc0, 0, 0, 0);
        acc1 = __builtin_amdgcn_mfma_f32_32x32x16_bf16(af, bf1, acc1, 0, 0, 0);
    }

    // C/D layout (verified, guide §3): col = lane&31, row = (j&3)+8*(j>>2)+4*(lane>>5)
#pragma unroll
    for (int j = 0; j < 16; ++j) {
        const int rl = (j & 3) + 8 * (j >> 2) + 4 * kh;
        const size_t row = row0 + rl;
        float v0 = acc0[j] + b_s[r];
        float v1 = acc1[j] + b_s[32 + r];
        proj[row * MAP_M + r]      = (__bf16)fmaxf(v0, 0.f);
        proj[row * MAP_M + 32 + r] = (__bf16)fmaxf(v1, 0.f);
    }
}

// ---------------------------------------------------------------------------
// Kernel C: per batch b: out[512][4096] = proj_b[512][64] @ map_b[4096][64]^T.
// (scale already folded into proj). 128x128 block tile, 4 waves (2x2), each
// wave 64x64 = 2x2 fragments of 32x32, K=64 = 4 MFMA k-steps.
// mapfeat f32 -> bf16 converted inline. Block order (b, st, ut) so the 4
// u-tile blocks sharing a map s-tile are consecutive (L2 reuse).
// ---------------------------------------------------------------------------
__global__ __launch_bounds__(256) void logit_kernel(
    const __bf16* __restrict__ proj,    // [32, 512, 64] bf16
    const float* __restrict__ mapfeat,  // [32, 4096, 64] f32
    float* __restrict__ out)            // [32, 512, 4096] f32
{
    const int bid = blockIdx.x;
    const int ut = bid & 3;             // 4 u-tiles of 128
    const int st = (bid >> 2) & 31;     // 32 s-tiles of 128
    const int b  = bid >> 7;            // 32 batches

    const int wave = threadIdx.x >> 6;
    const int lane = threadIdx.x & 63;
    const int wr = wave >> 1;
    const int wc = wave & 1;
    const int r  = lane & 31;
    const int kh = lane >> 5;

    const int u0 = ut * 128 + wr * 64;
    const int s0 = st * 128 + wc * 64;

    const __bf16* A = proj + (size_t)b * U_DIM * MAP_M;
    const float*  Bm = mapfeat + (size_t)b * S_DIM * MAP_M;

    f32x16 acc00 = {}, acc01 = {}, acc10 = {}, acc11 = {};

    const __bf16* a0p = A + (size_t)(u0 + r) * MAP_M + kh * 8;
    const __bf16* a1p = A + (size_t)(u0 + 32 + r) * MAP_M + kh * 8;
    const float*  b0p = Bm + (size_t)(s0 + r) * MAP_M + kh * 8;
    const float*  b1p = Bm + (size_t)(s0 + 32 + r) * MAP_M + kh * 8;

#pragma unroll
    for (int k = 0; k < MAP_M; k += 16) {
        bf16x8 a0 = *(const bf16x8*)(a0p + k);
        bf16x8 a1 = *(const bf16x8*)(a1p + k);
        float4 q0 = *(const float4*)(b0p + k);
        float4 q1 = *(const float4*)(b0p + k + 4);
        float4 q2 = *(const float4*)(b1p + k);
        float4 q3 = *(const float4*)(b1p + k + 4);
        bf16x8 bf0, bf1;
        bf0[0] = (__bf16)q0.x; bf0[1] = (__bf16)q0.y;
        bf0[2] = (__bf16)q0.z; bf0[3] = (__bf16)q0.w;
        bf0[4] = (__bf16)q1.x; bf0[5] = (__bf16)q1.y;
        bf0[6] = (__bf16)q1.z; bf0[7] = (__bf16)q1.w;
        bf1[0] = (__bf16)q2.x; bf1[1] = (__bf16)q2.y;
        bf1[2] = (__bf16)q2.z; bf1[3] = (__bf16)q2.w;
        bf1[4] = (__bf16)q3.x; bf1[5] = (__bf16)q3.y;
        bf1[6] = (__bf16)q3.z; bf1[7] = (__bf16)q3.w;
        acc00 = __builtin_amdgcn_mfma_f32_32x32x16_bf16(a0, bf0, acc00, 0, 0, 0);
        acc01 = __builtin_amdgcn_mfma_f32_32x32x16_bf16(a0, bf1, acc01, 0, 0, 0);
        acc10 = __builtin_amdgcn_mfma_f32_32x32x16_bf16(a1, bf0, acc10, 0, 0, 0);
        acc11 = __builtin_amdgcn_mfma_f32_32x32x16_bf16(a1, bf1, acc11, 0, 0, 0);
    }

    float* O = out + (size_t)b * U_DIM * S_DIM;
#pragma unroll
    for (int j = 0; j < 16; ++j) {
        const int rl = (j & 3) + 8 * (j >> 2) + 4 * kh;
        const size_t row0 = u0 + rl;
        const size_t row1 = u0 + 32 + rl;
        O[row0 * S_DIM + s0 + r]      = acc00[j];
        O[row0 * S_DIM + s0 + 32 + r] = acc01[j];
        O[row1 * S_DIM + s0 + r]      = acc10[j];
        O[row1 * S_DIM + s0 + 32 + r] = acc11[j];
    }
}

// ---------------------------------------------------------------------------
extern "C" void kernel_launch(void* const* d_in, const int* in_sizes, int n_in,
                              void* d_out, int out_size, void* d_ws, size_t ws_size,
                              hipStream_t stream) {
    const float* ufeat   = (const float*)d_in[0];   // [32,512,256]
    const float* mapfeat = (const float*)d_in[1];   // [32,4096,64]
    const float* v_w     = (const float*)d_in[2];   // [64,256]
    const float* g       = (const float*)d_in[3];   // [1]
    const float* b       = (const float*)d_in[4];   // [64]
    float* out = (float*)d_out;                     // [32,512,4096]

    __bf16* w_bf16 = (__bf16*)d_ws;                          // 32 KB
    float*  b_s    = (float*)((char*)d_ws + 32768);          // 256 B
    __bf16* proj   = (__bf16*)((char*)d_ws + 65536);         // 2 MB

    prep_kernel<<<1, 256, 0, stream>>>(v_w, g, b, w_bf16, b_s);
    proj_kernel<<<128, 256, 0, stream>>>(ufeat, w_bf16, b_s, proj);
    logit_kernel<<<B_DIM * 32 * 4, 256, 0, stream>>>(proj, mapfeat, out);
}

// Round 3
// 328.490 us; speedup vs baseline: 1.1282x; 1.1282x over previous
//
#include <hip/hip_runtime.h>
#include <hip/hip_bf16.h>

typedef __bf16 bf16x8 __attribute__((ext_vector_type(8)));
typedef float  f32x16 __attribute__((ext_vector_type(16)));
typedef float  f32x4  __attribute__((ext_vector_type(4)));

#define UF_D 256
#define MAP_M 64
#define B_DIM 32
#define U_DIM 512
#define S_DIM 4096

// ---------------------------------------------------------------------------
// Kernel 1: block 0 -> weight-norm scale (g/||V||/8 folded into w and b),
// emit w_bf16[64][256], b_s = b/8. Blocks 1..255 -> convert mapfeat f32->bf16
// (32 MB -> 16 MB) so the big GEMM reads half the bytes and does no converts.
// ---------------------------------------------------------------------------
__global__ __launch_bounds__(256) void prep_conv_kernel(
    const float* __restrict__ v_w, const float* __restrict__ g,
    const float* __restrict__ b, const float* __restrict__ mapfeat,
    __bf16* __restrict__ w_bf16, float* __restrict__ b_s,
    __bf16* __restrict__ map_bf16)
{
    const int t = threadIdx.x;
    if (blockIdx.x == 0) {
        __shared__ float red[256];
        const f32x4* v4 = (const f32x4*)v_w;   // 16384 f32 = 4096 float4
        float ss = 0.f;
        for (int i = t; i < 4096; i += 256) {
            f32x4 v = v4[i];
            ss += v.x * v.x + v.y * v.y + v.z * v.z + v.w * v.w;
        }
        red[t] = ss;
        __syncthreads();
        for (int s = 128; s > 0; s >>= 1) {
            if (t < s) red[t] += red[t + s];
            __syncthreads();
        }
        const float scale = g[0] / (sqrtf(red[0]) * 8.0f);
        for (int i = t; i < 4096; i += 256) {
            f32x4 v = v4[i];
            w_bf16[4 * i + 0] = (__bf16)(v.x * scale);
            w_bf16[4 * i + 1] = (__bf16)(v.y * scale);
            w_bf16[4 * i + 2] = (__bf16)(v.z * scale);
            w_bf16[4 * i + 3] = (__bf16)(v.w * scale);
        }
        if (t < MAP_M) b_s[t] = b[t] * 0.125f;
    } else {
        const int NC = (B_DIM * S_DIM * MAP_M) / 8;   // 1,048,576 chunks of 8
        const f32x4* m4 = (const f32x4*)mapfeat;
        bf16x8* o8 = (bf16x8*)map_bf16;
        for (int c = (blockIdx.x - 1) * 256 + t; c < NC; c += 255 * 256) {
            f32x4 q0 = __builtin_nontemporal_load(&m4[2 * c]);
            f32x4 q1 = __builtin_nontemporal_load(&m4[2 * c + 1]);
            bf16x8 o;
            o[0] = (__bf16)q0.x; o[1] = (__bf16)q0.y;
            o[2] = (__bf16)q0.z; o[3] = (__bf16)q0.w;
            o[4] = (__bf16)q1.x; o[5] = (__bf16)q1.y;
            o[6] = (__bf16)q1.z; o[7] = (__bf16)q1.w;
            o8[c] = o;
        }
    }
}

// ---------------------------------------------------------------------------
// Kernel 2: proj[16384][64] = relu(ufeat @ w^T + b/8) in bf16.
// 256 blocks x 64 rows (full GPU). 4 waves: (wr,wc) 2x2, each one 32x32
// output fragment, K=256 -> 16 MFMA. Nontemporal ufeat loads (streaming).
// ---------------------------------------------------------------------------
__global__ __launch_bounds__(256) void proj_kernel(
    const float* __restrict__ ufeat,    // [16384, 256] f32
    const __bf16* __restrict__ w,       // [64, 256] bf16 (pre-scaled)
    const float* __restrict__ b_s,      // [64] f32 (b/8)
    __bf16* __restrict__ proj)          // [16384, 64] bf16
{
    const int wave = threadIdx.x >> 6;
    const int lane = threadIdx.x & 63;
    const int r  = lane & 31;
    const int kh = lane >> 5;
    const int wr = wave >> 1, wc = wave & 1;
    const int row0 = blockIdx.x * 64 + wr * 32;
    const int col0 = wc * 32;

    f32x16 acc = {};
    const float*  ap = ufeat + (size_t)(row0 + r) * UF_D + kh * 8;
    const __bf16* wp = w + (col0 + r) * UF_D + kh * 8;

#pragma unroll
    for (int k = 0; k < UF_D; k += 16) {
        f32x4 a01 = __builtin_nontemporal_load((const f32x4*)(ap + k));
        f32x4 a23 = __builtin_nontemporal_load((const f32x4*)(ap + k + 4));
        bf16x8 af;
        af[0] = (__bf16)a01.x; af[1] = (__bf16)a01.y;
        af[2] = (__bf16)a01.z; af[3] = (__bf16)a01.w;
        af[4] = (__bf16)a23.x; af[5] = (__bf16)a23.y;
        af[6] = (__bf16)a23.z; af[7] = (__bf16)a23.w;
        bf16x8 wf = *(const bf16x8*)(wp + k);
        acc = __builtin_amdgcn_mfma_f32_32x32x16_bf16(af, wf, acc, 0, 0, 0);
    }

    // C/D layout: col = lane&31, row = (j&3)+8*(j>>2)+4*(lane>>5)
#pragma unroll
    for (int j = 0; j < 16; ++j) {
        const int rl = (j & 3) + 8 * (j >> 2) + 4 * kh;
        const size_t row = row0 + rl;
        const int col = col0 + r;
        float v = acc[j] + b_s[col];
        proj[row * MAP_M + col] = (__bf16)fmaxf(v, 0.f);
    }
}

// ---------------------------------------------------------------------------
// Kernel 3: per batch: out[512][4096] = proj_b[512][64] @ map_b[4096][64]^T
// (scale pre-folded). 128x128 tile, 4 waves (2x2), each 64x64 = 2x2 frags.
// All-bf16 operands. Bijective XCD swizzle (4096%8==0) so the 4 u-tiles
// sharing a map s-tile run on the same XCD L2. Nontemporal f32 stores so
// the 268 MB output stream doesn't evict proj/map from L2.
// ---------------------------------------------------------------------------
__global__ __launch_bounds__(256) void logit_kernel(
    const __bf16* __restrict__ proj,    // [32, 512, 64] bf16
    const __bf16* __restrict__ map,     // [32, 4096, 64] bf16
    float* __restrict__ out)            // [32, 512, 4096] f32
{
    const int vid = (blockIdx.x & 7) * 512 + (blockIdx.x >> 3);  // XCD swizzle
    const int ut = vid & 3;
    const int st = (vid >> 2) & 31;
    const int b  = vid >> 7;

    const int wave = threadIdx.x >> 6;
    const int lane = threadIdx.x & 63;
    const int wr = wave >> 1, wc = wave & 1;
    const int r  = lane & 31;
    const int kh = lane >> 5;

    const int u0 = ut * 128 + wr * 64;
    const int s0 = st * 128 + wc * 64;

    const __bf16* A  = proj + (size_t)b * U_DIM * MAP_M;
    const __bf16* Bm = map  + (size_t)b * S_DIM * MAP_M;

    f32x16 acc00 = {}, acc01 = {}, acc10 = {}, acc11 = {};

    const __bf16* a0p = A  + (size_t)(u0 + r)      * MAP_M + kh * 8;
    const __bf16* a1p = A  + (size_t)(u0 + 32 + r) * MAP_M + kh * 8;
    const __bf16* b0p = Bm + (size_t)(s0 + r)      * MAP_M + kh * 8;
    const __bf16* b1p = Bm + (size_t)(s0 + 32 + r) * MAP_M + kh * 8;

#pragma unroll
    for (int k = 0; k < MAP_M; k += 16) {
        bf16x8 a0 = *(const bf16x8*)(a0p + k);
        bf16x8 a1 = *(const bf16x8*)(a1p + k);
        bf16x8 f0 = *(const bf16x8*)(b0p + k);
        bf16x8 f1 = *(const bf16x8*)(b1p + k);
        acc00 = __builtin_amdgcn_mfma_f32_32x32x16_bf16(a0, f0, acc00, 0, 0, 0);
        acc01 = __builtin_amdgcn_mfma_f32_32x32x16_bf16(a0, f1, acc01, 0, 0, 0);
        acc10 = __builtin_amdgcn_mfma_f32_32x32x16_bf16(a1, f0, acc10, 0, 0, 0);
        acc11 = __builtin_amdgcn_mfma_f32_32x32x16_bf16(a1, f1, acc11, 0, 0, 0);
    }

    float* O = out + (size_t)b * U_DIM * S_DIM;
#pragma unroll
    for (int j = 0; j < 16; ++j) {
        const int rl = (j & 3) + 8 * (j >> 2) + 4 * kh;
        const size_t row0 = u0 + rl;
        const size_t row1 = u0 + 32 + rl;
        __builtin_nontemporal_store(acc00[j], &O[row0 * S_DIM + s0 + r]);
        __builtin_nontemporal_store(acc01[j], &O[row0 * S_DIM + s0 + 32 + r]);
        __builtin_nontemporal_store(acc10[j], &O[row1 * S_DIM + s0 + r]);
        __builtin_nontemporal_store(acc11[j], &O[row1 * S_DIM + s0 + 32 + r]);
    }
}

// ---------------------------------------------------------------------------
extern "C" void kernel_launch(void* const* d_in, const int* in_sizes, int n_in,
                              void* d_out, int out_size, void* d_ws, size_t ws_size,
                              hipStream_t stream) {
    const float* ufeat   = (const float*)d_in[0];   // [32,512,256]
    const float* mapfeat = (const float*)d_in[1];   // [32,4096,64]
    const float* v_w     = (const float*)d_in[2];   // [64,256]
    const float* g       = (const float*)d_in[3];   // [1]
    const float* b       = (const float*)d_in[4];   // [64]
    float* out = (float*)d_out;                     // [32,512,4096]

    __bf16* w_bf16   = (__bf16*)d_ws;                               // 32 KB
    float*  b_s      = (float*)((char*)d_ws + 32768);               // 256 B
    __bf16* proj     = (__bf16*)((char*)d_ws + 65536);              // 2 MB
    __bf16* map_bf16 = (__bf16*)((char*)d_ws + 65536 + 2097152);    // 16 MB

    prep_conv_kernel<<<256, 256, 0, stream>>>(v_w, g, b, mapfeat, w_bf16, b_s, map_bf16);
    proj_kernel<<<256, 256, 0, stream>>>(ufeat, w_bf16, b_s, proj);
    logit_kernel<<<B_DIM * 32 * 4, 256, 0, stream>>>(proj, map_bf16, out);
}